// Round 12
// baseline (3904.240 us; speedup 1.0000x reference)
//
#include <hip/hip_runtime.h>
#include <stdint.h>

// FPS (farthest point sampling), faithful to the reference:
//   dist = max(dist, ||p - last||)  (running MAX, per tf.maximum quirk)
//   idx  = argmax(dist)             (first-index tie-break)
// B=16, N=65536, npoint=1024 -> 1023 sequential rounds per batch.
//
// Round 9 changes (serial-chain cuts; round-8 evidence = latency-bound):
//  1. B2 barrier + wc[] LDS broadcast REMOVED: all 8 waves redundantly
//     poll the 64 slot words (1 u64/lane) and redundantly extract the
//     winner via shfl -> coords land in registers of every wave with no
//     broadcast. Only B1 (block argmax reduce) remains per step.
//  2. Double-sampled poll: two back-to-back atomic loads per spin iter,
//     checked in order -> halves the ~600cy retry quantization.
// Kept from round 8: points in LDS SoA (48 KB), coords-in-slot publish,
// step-parity double-buffered slots, sqrtf (sq-compare rejected: sqrt
// rounding collisions would break first-index tie-break vs numpy).
// Liveness audit (round 10): poll guard-bounded; uniform barrier counts;
// parity overwrite provably ordered after batch-wide poll completion.

#define B_      16
#define N_      65536
#define STEPS   1023       // npoint - 1
#define KBLK    16         // blocks per batch
#define THREADS 512
#define PPT     8          // points per thread = N_/KBLK/THREADS
#define PTS     4096       // points per block
#define NW      (THREADS/64)   // 8 waves

__global__ void zero_slots(unsigned long long* ws, int n) {
    int i = blockIdx.x * blockDim.x + threadIdx.x;
    if (i < n) ws[i] = 0ull;
}

__launch_bounds__(THREADS)
__global__ void fps_kernel(const float* __restrict__ xyz,
                           float* __restrict__ out,
                           unsigned long long* __restrict__ slots) {
    #pragma clang fp contract(off)

    const int blk  = blockIdx.x;
    const int b    = blk >> 4;     // batch
    const int k    = blk & 15;     // sub-block within batch
    const int tid  = threadIdx.x;
    const int wid  = tid >> 6;
    const int lane = tid & 63;

    const float* bx = xyz + (size_t)b * (N_ * 3);

    __shared__ float spx[PTS], spy[PTS], spz[PTS];   // 48 KB
    __shared__ float lval[NW];
    __shared__ int   lidx[NW];

    // ---- one-time: coalesced 96B/thread global read, scatter to LDS SoA ----
    {
        const float4* src = (const float4*)(bx + (size_t)(k * PTS + tid * PPT) * 3);
        float a[24];
        #pragma unroll
        for (int j = 0; j < 6; ++j) {
            float4 v = src[j];
            a[4*j+0] = v.x; a[4*j+1] = v.y; a[4*j+2] = v.z; a[4*j+3] = v.w;
        }
        #pragma unroll
        for (int p = 0; p < PPT; ++p) {
            int l = tid * PPT + p;
            spx[l] = a[3*p]; spy[l] = a[3*p+1]; spz[l] = a[3*p+2];
        }
    }
    float dist[PPT];
    #pragma unroll
    for (int p = 0; p < PPT; ++p) dist[p] = 0.0f;

    // initial center = point 0 of this batch
    float cx = bx[0], cy = bx[1], cz = bx[2];

    float* bout = out + (size_t)b * (1024 * 3);
    if (k == 0 && tid == 0) { bout[0] = cx; bout[1] = cy; bout[2] = cz; }
    __syncthreads();   // LDS points ready

    // slot layout: [parity][batch][word 0..3][block 0..15] u64
    unsigned long long* base = slots + (size_t)b * (4 * KBLK);
    const size_t parStride = (size_t)B_ * 4 * KBLK;   // u64s per parity buffer

    for (int s = 0; s < STEPS; ++s) {
        // ---- local update + local argmax (ascending l => first-max) ----
        float bv = -1.0f; int bl = 0;
        #pragma unroll
        for (int j = 0; j < PPT; ++j) {
            int l = tid + j * THREADS;            // stride-512: conflict-free
            float x = spx[l], y = spy[l], z = spz[l];
            float dx = x - cx, dy = y - cy, dz = z - cz;
            float sq = dx*dx + dy*dy + dz*dz;     // no fma (contract off)
            float d  = sqrtf(sq);                 // correctly-rounded
            float nd = fmaxf(dist[j], d);
            dist[j] = nd;
            if (nd > bv) { bv = nd; bl = l; }     // strict > keeps smallest l
        }
        int gi = k * PTS + bl;                    // within-batch global index

        // ---- wave reduce (val desc, idx asc on tie) ----
        #pragma unroll
        for (int m = 1; m < 64; m <<= 1) {
            float ov = __shfl_xor(bv, m);
            int   oi = __shfl_xor(gi, m);
            if (ov > bv || (ov == bv && oi < gi)) { bv = ov; gi = oi; }
        }
        if (lane == 0) { lval[wid] = bv; lidx[wid] = gi; }
        __syncthreads();   // B1 — the only barrier per step

        unsigned long long* cur = base + (size_t)(s & 1) * parStride;

        if (wid == 0) {
            float v2 = (lane < NW) ? lval[lane] : -1.0f;
            int   i2 = (lane < NW) ? lidx[lane] : 0x7FFFFFFF;
            #pragma unroll
            for (int m = 1; m < NW; m <<= 1) {
                float ov = __shfl_xor(v2, m);
                int   oi = __shfl_xor(i2, m);
                if (ov > v2 || (ov == v2 && oi < i2)) { v2 = ov; i2 = oi; }
            }
            // block best (v2, i2) known in all lanes of wave 0.
            // Winner coords from own LDS (uniform addr = broadcast read).
            int li = i2 & (PTS - 1);
            float wx = spx[li], wy = spy[li], wz = spz[li];

            // publish 4 self-tagged words; u64-max on word A implements
            // (max val, tie -> min idx); tag == s+1 validates freshness.
            unsigned long long tag = (unsigned long long)(s + 1) << 48;
            unsigned long long A  = tag |
                ((unsigned long long)__float_as_uint(v2) << 16) |
                (unsigned long long)(0xFFFFu ^ (unsigned)i2);
            unsigned long long Bw = tag | (unsigned long long)__float_as_uint(wx);
            unsigned long long Cw = tag | (unsigned long long)__float_as_uint(wy);
            unsigned long long Dw = tag | (unsigned long long)__float_as_uint(wz);

            unsigned long long pub = (lane == 0) ? A :
                                     (lane == 1) ? Bw :
                                     (lane == 2) ? Cw : Dw;
            if (lane < 4)
                __hip_atomic_store(&cur[lane * KBLK + k], pub,
                                   __ATOMIC_RELAXED, __HIP_MEMORY_SCOPE_AGENT);
        }

        // ---- ALL waves: redundant poll + extract (no broadcast barrier).
        // lane i watches word (i>>4) of block (i&15) — coalesced.
        const unsigned long long want = (unsigned long long)(s + 1);
        unsigned long long pw;
        {
            unsigned long long p1, p2;
            int guard = 0;
            for (;;) {
                p1 = __hip_atomic_load(&cur[lane],
                                       __ATOMIC_RELAXED, __HIP_MEMORY_SCOPE_AGENT);
                p2 = __hip_atomic_load(&cur[lane],
                                       __ATOMIC_RELAXED, __HIP_MEMORY_SCOPE_AGENT);
                if (__all((p1 >> 48) == want)) { pw = p1; break; }
                if (__all((p2 >> 48) == want)) { pw = p2; break; }
                if (++guard > 200000) { pw = p2; break; }   // bounds any stall
            }
        }
        // A-word max within the 16-lane group (masks <=8 stay in-group)
        unsigned long long mm = pw;
        #pragma unroll
        for (int m = 1; m < 16; m <<= 1) {
            unsigned long long o = __shfl_xor(mm, m);
            if (o > mm) mm = o;
        }
        int gidx = 0xFFFF ^ (int)(mm & 0xFFFFull);  // valid in lanes 0-15
        gidx = __shfl(gidx, 0);
        int w = gidx >> 12;                         // winning block
        unsigned xlo = (unsigned)__shfl((int)(unsigned)pw, 16 + w);
        unsigned ylo = (unsigned)__shfl((int)(unsigned)pw, 32 + w);
        unsigned zlo = (unsigned)__shfl((int)(unsigned)pw, 48 + w);
        cx = __uint_as_float(xlo);
        cy = __uint_as_float(ylo);
        cz = __uint_as_float(zlo);

        if (k == 0 && tid == 0) {
            float* o = bout + (size_t)(s + 1) * 3;
            o[0] = cx; o[1] = cy; o[2] = cz;
        }
    }
}

extern "C" void kernel_launch(void* const* d_in, const int* in_sizes, int n_in,
                              void* d_out, int out_size, void* d_ws, size_t ws_size,
                              hipStream_t stream) {
    const float* xyz = (const float*)d_in[0];
    float* out = (float*)d_out;
    unsigned long long* slots = (unsigned long long*)d_ws;

    const int nslots = 2 * B_ * 4 * KBLK;   // 2048 u64 = 16 KB
    zero_slots<<<(nslots + 255) / 256, 256, 0, stream>>>(slots, nslots);
    fps_kernel<<<B_ * KBLK, THREADS, 0, stream>>>(xyz, out, slots);
}